// Round 12
// baseline (334.668 us; speedup 1.0000x reference)
//
#include <hip/hip_runtime.h>

// Problem constants (fixed by the reference)
#define NN 32768      // nodes
#define EE 262144     // edges
#define DM 512        // input/model dim (K of the big GEMM)
#define NQKV 1536     // q|k|v concatenated
#define NHEAD 8
#define DHEAD 64

typedef unsigned short u16;
typedef unsigned int u32;
typedef __attribute__((ext_vector_type(8))) short bf16x8;   // MFMA A/B operand (8 bf16)
typedef __attribute__((ext_vector_type(4))) float f32x4;    // MFMA C/D
typedef __attribute__((ext_vector_type(8))) u16 u16x8;
typedef __attribute__((ext_vector_type(4))) u32 u32x4;

__device__ __forceinline__ float bf2f(u16 u) {
  union { u32 i; float f; } x; x.i = ((u32)u) << 16; return x.f;
}
__device__ __forceinline__ float bflo(u32 p) {
  union { u32 i; float f; } x; x.i = p << 16; return x.f;
}
__device__ __forceinline__ float bfhi(u32 p) {
  union { u32 i; float f; } x; x.i = p & 0xFFFF0000u; return x.f;
}
__device__ __forceinline__ u16 f2bf(float f) {
  union { float f; u32 i; } x; x.f = f;
  u32 r = x.i + 0x7FFFu + ((x.i >> 16) & 1u);   // RNE
  return (u16)(r >> 16);
}

__device__ __forceinline__ void load_lds16(const u16* g, u16* l) {
  __builtin_amdgcn_global_load_lds(
      (const __attribute__((address_space(1))) char*)(const void*)g,
      (__attribute__((address_space(3))) char*)(void*)l, 16, 0, 0);
}

// XOR chunk swizzle for the 4x16B chunks of a 32-elem LDS row (128^2 kernels).
__device__ __forceinline__ int swz(int r, int s) {
  return s ^ (r & 3) ^ ((r >> 2) & 1);
}

// ---------------------------------------------------------------------------
// prep_all: all independent preprocessing in ONE launch (R5 verbatim).
// ---------------------------------------------------------------------------
#define GB_CASTH 8192
#define GB_CASTW 128
#define GB_CNTD  1024
#define GB_TCW   192
#define GB_BIAS  96
__global__ void prep_all(const float* __restrict__ h, u16* __restrict__ hb,
                         const float* __restrict__ Win, u16* __restrict__ Winb,
                         const int* __restrict__ row, int* __restrict__ deg,
                         const float* __restrict__ Wq, const float* __restrict__ Wk,
                         const float* __restrict__ Wv, u16* __restrict__ At,
                         const float* __restrict__ bin, const float* __restrict__ bq,
                         const float* __restrict__ bk, const float* __restrict__ bv,
                         float* __restrict__ bias) {
  __shared__ float t[64][65];
  const int tid = threadIdx.x;
  int b = blockIdx.x;

  if (b < GB_CASTH) {                       // ---- cast_h ----
    const int i = (b * 256 + tid) * 8;
    float4 a = *(const float4*)&h[i];
    float4 c = *(const float4*)&h[i + 4];
    u16x8 o = { f2bf(a.x), f2bf(a.y), f2bf(a.z), f2bf(a.w),
                f2bf(c.x), f2bf(c.y), f2bf(c.z), f2bf(c.w) };
    *(u16x8*)&hb[i] = o;
    return;
  }
  b -= GB_CASTH;
  if (b < GB_CASTW) {                       // ---- cast_win ----
    const int i = (b * 256 + tid) * 8;
    float4 a = *(const float4*)&Win[i];
    float4 c = *(const float4*)&Win[i + 4];
    u16x8 o = { f2bf(a.x), f2bf(a.y), f2bf(a.z), f2bf(a.w),
                f2bf(c.x), f2bf(c.y), f2bf(c.z), f2bf(c.w) };
    *(u16x8*)&Winb[i] = o;
    return;
  }
  b -= GB_CASTW;
  if (b < GB_CNTD) {                        // ---- count_deg ----
    const int e = b * 256 + tid;
    atomicAdd(&deg[row[e]], 1);
    return;
  }
  b -= GB_CNTD;
  if (b < GB_TCW) {                         // ---- tcast_w ----
    const int z = b / 64;                   // 0=q,1=k,2=v
    const int r64 = b % 64;
    const float* W = (z == 0) ? Wq : (z == 1) ? Wk : Wv;
    const float scale = (z == 0) ? 0.125f : 1.0f;
    const int m0 = (r64 >> 3) * 64;
    const int j0 = (r64 & 7) * 64;
    const int tx = tid & 63, ty = tid >> 6;
#pragma unroll
    for (int i = 0; i < 16; ++i) {
      const int r = ty * 16 + i;
      t[r][tx] = W[(size_t)(m0 + r) * 512 + (j0 + tx)];   // coalesced over tx
    }
    __syncthreads();
#pragma unroll
    for (int i = 0; i < 16; ++i) {
      const int j = j0 + ty * 16 + i;
      const int pr = (z == 0) ? j : (512 + 2 * j + (z - 1));  // permuted row
      At[(size_t)pr * 512 + (m0 + tx)] = f2bf(t[tx][ty * 16 + i] * scale);
    }
    return;
  }
  b -= GB_TCW;
  {                                         // ---- make_bias partial ----
    const int j = (b % 6) * 256 + tid;      // logical output index 0..1535
    const int m0 = (b / 6) * 32;            // this block's K-slice
    const float* Wsel; const float* bsel; int jj; float scale = 1.0f; int pos;
    if (j < 512)       { Wsel = Wq; bsel = bq; jj = j;        scale = 0.125f; pos = j; }
    else if (j < 1024) { Wsel = Wk; bsel = bk; jj = j - 512;  pos = 512 + 2 * jj; }
    else               { Wsel = Wv; bsel = bv; jj = j - 1024; pos = 513 + 2 * jj; }
    float s0 = 0.f, s1 = 0.f, s2 = 0.f, s3 = 0.f;
#pragma unroll
    for (int m = 0; m < 32; m += 4) {
      s0 = fmaf(bin[m0 + m],     Wsel[(size_t)(m0 + m)     * 512 + jj], s0);
      s1 = fmaf(bin[m0 + m + 1], Wsel[(size_t)(m0 + m + 1) * 512 + jj], s1);
      s2 = fmaf(bin[m0 + m + 2], Wsel[(size_t)(m0 + m + 2) * 512 + jj], s2);
      s3 = fmaf(bin[m0 + m + 3], Wsel[(size_t)(m0 + m + 3) * 512 + jj], s3);
    }
    float add = ((s0 + s1) + (s2 + s3)) * scale;
    if (m0 == 0) add += bsel[jj] * scale;
    atomicAdd(&bias[pos], add);
  }
}

// ---------------------------------------------------------------------------
// CSR build on `row` (scan + fill; counting folded into prep_all)
// ---------------------------------------------------------------------------
__global__ void scan_deg(const int* __restrict__ deg, int* __restrict__ row_ptr,
                         int* __restrict__ cursor) {
  __shared__ int sums[1024];
  const int t = threadIdx.x;
  const int base = t * 32;
  int loc[32];
  int s = 0;
#pragma unroll
  for (int i = 0; i < 32; ++i) { loc[i] = s; s += deg[base + i]; }
  sums[t] = s;
  __syncthreads();
  for (int off = 1; off < 1024; off <<= 1) {
    int v = (t >= off) ? sums[t - off] : 0;
    __syncthreads();
    sums[t] += v;
    __syncthreads();
  }
  const int excl = sums[t] - s;
#pragma unroll
  for (int i = 0; i < 32; ++i) {
    const int val = excl + loc[i];
    row_ptr[base + i] = val;
    cursor[base + i] = val;
  }
  if (t == 1023) row_ptr[NN] = sums[1023];
}

__global__ void fill_csr(const int* __restrict__ row, const int* __restrict__ col,
                         int* __restrict__ cursor, int* __restrict__ dst) {
  const int e = blockIdx.x * 256 + threadIdx.x;
  const int r = row[e];
  const int p = atomicAdd(&cursor[r], 1);
  dst[p] = col[e];
}

// ---------------------------------------------------------------------------
// Compose GEMM: Wt[j][kk] = sum_m At[j][m] * Winb[kk][m]
// M=1536, N=512, K=512. 128^2 + 2-phase pipeline (R5-proven form).
// ---------------------------------------------------------------------------
__global__ __launch_bounds__(256, 2) void gemm_wt(
    const u16* __restrict__ A,    // At [1536][512] bf16 (rows pre-permuted)
    const u16* __restrict__ B,    // Winb [512][512] bf16 (B^T layout)
    u16* __restrict__ C) {        // Wt [1536][512] bf16
  __shared__ u16 As[2][128 * 32];
  __shared__ u16 Bs[2][128 * 32];
  const int tid = threadIdx.x;
  const int lane = tid & 63;
  const int wave = tid >> 6;
  const int quad = lane >> 4;
  const int l16 = lane & 15;
  const int m0 = blockIdx.y * 128;
  const int n0 = blockIdx.x * 128;
  const int wm = (wave >> 1) * 64;
  const int wn = (wave & 1) * 64;

  const int c0 = tid, c1 = tid + 256;
  const int r0 = c0 >> 2, ko0 = swz(r0, c0 & 3) * 8;
  const int r1 = c1 >> 2, ko1 = swz(r1, c1 & 3) * 8;
  const u16* Ag0 = A + (size_t)(m0 + r0) * DM + ko0;
  const u16* Ag1 = A + (size_t)(m0 + r1) * DM + ko1;
  const u16* Bg0 = B + (size_t)(n0 + r0) * DM + ko0;
  const u16* Bg1 = B + (size_t)(n0 + r1) * DM + ko1;

  f32x4 acc[4][4];
#pragma unroll
  for (int i = 0; i < 4; ++i)
#pragma unroll
    for (int j = 0; j < 4; ++j) acc[i][j] = (f32x4){0.f, 0.f, 0.f, 0.f};

  load_lds16(Ag0, &As[0][c0 * 8]);
  load_lds16(Bg0, &Bs[0][c0 * 8]);
  load_lds16(Ag1, &As[0][c1 * 8]);
  load_lds16(Bg1, &Bs[0][c1 * 8]);
  __syncthreads();

  int cur = 0;
#pragma unroll
  for (int kt = 32; kt < DM; kt += 32) {
    load_lds16(Ag0 + kt, &As[cur ^ 1][c0 * 8]);
    load_lds16(Bg0 + kt, &Bs[cur ^ 1][c0 * 8]);
    load_lds16(Ag1 + kt, &As[cur ^ 1][c1 * 8]);
    load_lds16(Bg1 + kt, &Bs[cur ^ 1][c1 * 8]);
    bf16x8 a[4], b[4];
#pragma unroll
    for (int i = 0; i < 4; ++i) {
      const int ra = wm + i * 16 + l16;
      const int rb = wn + i * 16 + l16;
      a[i] = *(const bf16x8*)&As[cur][ra * 32 + swz(ra, quad) * 8];
      b[i] = *(const bf16x8*)&Bs[cur][rb * 32 + swz(rb, quad) * 8];
    }
#pragma unroll
    for (int mi = 0; mi < 4; ++mi)
#pragma unroll
      for (int ni = 0; ni < 4; ++ni)
        acc[mi][ni] = __builtin_amdgcn_mfma_f32_16x16x32_bf16(a[mi], b[ni], acc[mi][ni], 0, 0, 0);
    __syncthreads();
    cur ^= 1;
  }
  {
    bf16x8 a[4], b[4];
#pragma unroll
    for (int i = 0; i < 4; ++i) {
      const int ra = wm + i * 16 + l16;
      const int rb = wn + i * 16 + l16;
      a[i] = *(const bf16x8*)&As[cur][ra * 32 + swz(ra, quad) * 8];
      b[i] = *(const bf16x8*)&Bs[cur][rb * 32 + swz(rb, quad) * 8];
    }
#pragma unroll
    for (int mi = 0; mi < 4; ++mi)
#pragma unroll
      for (int ni = 0; ni < 4; ++ni)
        acc[mi][ni] = __builtin_amdgcn_mfma_f32_16x16x32_bf16(a[mi], b[ni], acc[mi][ni], 0, 0, 0);
  }

#pragma unroll
  for (int ni = 0; ni < 4; ++ni) {
    const int coln = n0 + wn + ni * 16 + l16;
#pragma unroll
    for (int mi = 0; mi < 4; ++mi) {
#pragma unroll
      for (int r = 0; r < 4; ++r) {
        const int rowm = m0 + wm + mi * 16 + quad * 4 + r;
        C[(size_t)rowm * 512 + coln] = f2bf(acc[mi][ni][r]);
      }
    }
  }
}

// ---------------------------------------------------------------------------
// QKV = h_bf16 @ Wt^T + bias   (M=32768, N=1536, K=512)
// 256x256 tile, BK=64, 512 threads / 8 waves, 128 KiB LDS, deep pipeline.
//
// Slab schedule per K-tile t (dbuf d=t&1): 4 slabs of 64 rows; per slab each
// wave computes a 64x32 region with ROTATED col-block b=(w+p)&7 (regions
// partition the tile; accumulation per element keeps identical k-order ->
// bit-identical numerics vs the 128-tile kernels).
//
// Staging of K-tile t+1 targets dbuf (t+1)&1 whose readers (K-tile t-1)
// drained at t's first barrier (lgkmcnt(0)). Issue order per K-tile:
// [B0,B1]@P0, [A0]@mid-slab0, [A1]@P2. Derived counted waits:
//  - P0: all older than A1(t) complete -> vmcnt(2)  (needs B0,B1,A0 of t)
//  - P2: newer-than-A1(t) = B0B1(t+1)+A0(t+1) = 6 -> vmcnt(6) (needs A1 of t)
// Never drain-0 until t=7. 2 barriers/K-tile (17 total vs 33 in the 128-tile
// kernel), 64 MFMA/wave between waits, setprio around MFMA clusters (T5).
// Chunk-XOR swizzle: rh&7 == l16&7 -> fragment reads are 2-way (free).
// Epilogue: XOR-swizzled 128KB C-stage reuse + 16B coalesced streams.
// ---------------------------------------------------------------------------
__global__ __launch_bounds__(512, 1) void gemm_qkv(
    const u16* __restrict__ A,    // hb [32768][512] bf16, row-major
    const u16* __restrict__ B,    // Wt [1536][512] bf16, N-major, rows permuted
    const float* __restrict__ bias,  // permuted to match columns
    u16* __restrict__ C) {        // qkv [32768,1536] bf16 unified
  __shared__ __align__(16) u16 lds[65536];   // 128 KiB: A/B ring, then C-stage
  const int tid = threadIdx.x;
  const int lane = tid & 63;
  const int wave = tid >> 6;          // 0..7
  const int quad = lane >> 4;         // 0..3
  const int l16 = lane & 15;

  // XCD swizzle: 768 blocks = 8 XCDs x 96 (bijective).
  const int bid = blockIdx.y * 6 + blockIdx.x;
  const int sw = (bid & 7) * 96 + (bid >> 3);
  const int bx = sw % 6, by = sw / 6;
  const int m0 = by * 256, n0 = bx * 256;

  // staging: half-tile = [128 rows][64 k] bf16 = 1024 16B-slots; thread owns
  // slots tid (row r0) and tid+512 (row r0+64). LDS slot (r,ch) holds logical
  // k-chunk ch^(r&7); both slots share sc since 64%8==0.
  const int r0 = tid >> 3;                  // 0..63
  const int sc = (tid & 7) ^ (r0 & 7);
  const u16* Ag = A + (size_t)(m0 + r0) * DM + sc * 8;
  const u16* Bg = B + (size_t)(n0 + r0) * DM + sc * 8;
  const int ls0 = tid * 8, ls1 = ls0 + 4096;

#define AOFF(d, hh) (((d) * 2 + (hh)) * 8192)
#define BOFF(d, hh) (32768 + ((d) * 2 + (hh)) * 8192)
#define STAGE_A(t, hh) do { \
    load_lds16(Ag + (size_t)(hh) * 128 * DM + (t) * 64,            &lds[AOFF((t) & 1, (hh)) + ls0]); \
    load_lds16(Ag + (size_t)(hh) * 128 * DM + 64 * DM + (t) * 64,  &lds[AOFF((t) & 1, (hh)) + ls1]); } while (0)
#define STAGE_B(t, hh) do { \
    load_lds16(Bg + (size_t)(hh) * 128 * DM + (t) * 64,            &lds[BOFF((t) & 1, (hh)) + ls0]); \
    load_lds16(Bg + (size_t)(hh) * 128 * DM + 64 * DM + (t) * 64,  &lds[BOFF((t) & 1, (hh)) + ls1]); } while (0)

  // fragment per-lane bases: row-within-half rh has rh&7 == l16&7, so the
  // chunk XOR collapses to a per-lane constant per k-step.
  const int cx0 = ((quad ^ (l16 & 7)) * 8) + l16 * 64;          // ks=0
  const int cx1 = (((quad + 4) ^ (l16 & 7)) * 8) + l16 * 64;    // ks=1

  f32x4 acc[4][4][2];
#pragma unroll
  for (int p = 0; p < 4; ++p)
#pragma unroll
    for (int i = 0; i < 4; ++i)
#pragma unroll
      for (int j = 0; j < 2; ++j) acc[p][i][j] = (f32x4){0.f, 0.f, 0.f, 0.f};

#define SLAB(t, p) do { \
    const int _d = (t) & 1; \
    const int _ab = AOFF(_d, (p) >> 1) + ((p) & 1) * 4096; \
    const int _bk = (wave + (p)) & 7; \
    const int _bb = BOFF(_d, _bk >> 2) + (_bk & 3) * 2048; \
    bf16x8 a0[4], a1[4], b0[2], b1[2]; \
    _Pragma("unroll") for (int i = 0; i < 4; ++i) { \
      a0[i] = *(const bf16x8*)&lds[_ab + i * 1024 + cx0]; \
      a1[i] = *(const bf16x8*)&lds[_ab + i * 1024 + cx1]; } \
    _Pragma("unroll") for (int j = 0; j < 2; ++j) { \
      b0[j] = *(const bf16x8*)&lds[_bb + j * 1024 + cx0]; \
      b1[j] = *(const bf16x8*)&lds[_bb + j * 1024 + cx1]; } \
    __builtin_amdgcn_s_setprio(1); \
    _Pragma("unroll") for (int i = 0; i < 4; ++i) \
      _Pragma("unroll") for (int j = 0; j < 2; ++j) \
        acc[p][i][j] = __builtin_amdgcn_mfma_f32_16x16x32_bf16(a0[i], b0[j], acc[p][i][j], 0, 0, 0); \
    _Pragma("unroll") for (int i = 0; i < 4; ++i) \
      _Pragma("unroll") for (int j = 0; j < 2; ++j) \
        acc[p][i][j] = __builtin_amdgcn_mfma_f32_16x16x32_bf16(a1[i], b1[j], acc[p][i][j], 0, 0, 0); \
    __builtin_amdgcn_s_setprio(0); } while (0)

  // prologue: K-tile 0 in steady-state issue order [B0,B1,A0,A1]
  STAGE_B(0, 0); STAGE_B(0, 1); STAGE_A(0, 0); STAGE_A(0, 1);

#pragma unroll
  for (int t = 0; t < 8; ++t) {
    // P0: needs B0,B1,A0 of t (all older than A1(t)) -> vmcnt(2)
    asm volatile("s_waitcnt vmcnt(2) lgkmcnt(0)\ns_barrier" ::: "memory");
    if (t < 7) { STAGE_B(t + 1, 0); STAGE_B(t + 1, 1); }
    SLAB(t, 0);
    if (t < 7) { STAGE_A(t + 1, 0); }
    SLAB(t, 1);
    // P2: needs A1(t); newer = B0B1(t+1)+A0(t+1) = 6 (0 when t==7)
    if (t < 7) asm volatile("s_waitcnt vmcnt(6) lgkmcnt(0)\ns_barrier" ::: "memory");
    else       asm volatile("s_waitcnt vmcnt(0) lgkmcnt(0)\ns_barrier" ::: "memory");
    if (t < 7) { STAGE_A(t + 1, 1); }
    SLAB(t, 2);
    SLAB(t, 3);
  }

  // ---- epilogue: all waves' ds_reads drained, then reuse LDS as C-stage.
  asm volatile("s_waitcnt lgkmcnt(0)\ns_barrier" ::: "memory");
  // deposit: Cs[256][256] u16 with col XOR'd by 16B granule of (row>>2)
  // to spread the quad-row writes across banks; involution -> same XOR on read.
#pragma unroll
  for (int p = 0; p < 4; ++p) {
    const int bblk = (wave + p) & 7;
#pragma unroll
    for (int j = 0; j < 2; ++j) {
      const int col = bblk * 32 + j * 16 + l16;
      const float bv = bias[n0 + col];
#pragma unroll
      for (int i = 0; i < 4; ++i) {
#pragma unroll
        for (int r = 0; r < 4; ++r) {
          const int rr = p * 64 + i * 16 + quad * 4 + r;
          lds[rr * 256 + (col ^ (((rr >> 2) & 7) << 3))] = f2bf(acc[p][i][j][r] + bv);
        }
      }
    }
  }
  __syncthreads();
  // stream out: 8192 16B-chunks, consecutive lanes -> consecutive 16B.
#pragma unroll
  for (int k = 0; k < 16; ++k) {
    const int idx = k * 512 + tid;
    const int rr = idx >> 5;
    const int cc = (idx & 31) * 8;
    *(u16x8*)&C[(size_t)(m0 + rr) * NQKV + n0 + cc] =
        *(const u16x8*)&lds[rr * 256 + (cc ^ (((rr >> 2) & 7) << 3))];
  }
#undef SLAB
#undef STAGE_A
#undef STAGE_B
#undef AOFF
#undef BOFF
}

// ---------------------------------------------------------------------------
// Fused sparse attention: ONE WAVE PER NODE; lane l owns dims l*8..l*8+7.
// Round-1 proven form (CHUNK=4 clamped, VGPR 48): fastest of the measured
// structural variants (87-91 us, FETCH pinned 267 MB -> gather-bound).
// ---------------------------------------------------------------------------
__global__ __launch_bounds__(256) void attn_agg(
    const u16* __restrict__ qkv16, const u32* __restrict__ qkv32,
    const int* __restrict__ row_ptr, const int* __restrict__ dst,
    float* __restrict__ out) {
  const int gt = blockIdx.x * 256 + threadIdx.x;
  const int node = gt >> 6;
  const int lane = gt & 63;
  const u16x8 qr = *(const u16x8*)&qkv16[(size_t)node * NQKV + lane * 8];
  float qf[8];
#pragma unroll
  for (int j = 0; j < 8; ++j) qf[j] = bf2f(qr[j]);

  const int beg = row_ptr[node];
  const int end = row_ptr[node + 1];
  float acc[8] = {0.f,0.f,0.f,0.f,0.f,0.f,0.f,0.f};
  float denom = 0.f;

  for (int e = beg; e < end; e += 4) {
    u32 p[4][8];
    int idx[4];
#pragma unroll
    for (int jj = 0; jj < 4; ++jj) {
      const int ee = min(e + jj, end - 1);
      idx[jj] = dst[ee];
    }
#pragma unroll
    for (int jj = 0; jj < 4; ++jj) {
      const u32* pp = qkv32 + (size_t)idx[jj] * 768 + 256 + lane * 8;
      *(u32x4*)&p[jj][0] = *(const u32x4*)pp;        // dwordx4
      *(u32x4*)&p[jj][4] = *(const u32x4*)(pp + 4);  // dwordx4
    }
#pragma unroll
    for (int jj = 0; jj < 4; ++jj) {
      float s = 0.f;
#pragma unroll
      for (int j = 0; j < 8; ++j) s = fmaf(qf[j], bflo(p[jj][j]), s);
      s += __shfl_xor(s, 1, 64);   // reduce within the 8-lane head group
      s += __shfl_xor(s, 2, 64);
      s += __shfl_xor(s, 4, 64);
      const float ex = (e + jj < end) ? __expf(s) : 0.f;
      denom += ex;
#pragma unroll
      for (int j = 0; j < 8; ++j) acc[j] = fmaf(ex, bfhi(p[jj][j]), acc[j]);
    }
  }

  const float inv = (end > beg) ? (1.0f / denom) : 0.f;   // deg-0 rows -> 0
  float4 o0 = { acc[0] * inv, acc[1] * inv, acc[2] * inv, acc[3] * inv };
  float4 o1 = { acc[4] * inv, acc[5] * inv, acc[6] * inv, acc[7] * inv };
  float* op = &out[(size_t)node * 512 + lane * 8];
  *(float4*)op = o0;
  *(float4*)(op + 4) = o1;
}

// ---------------------------------------------------------------------------
extern "C" void kernel_launch(void* const* d_in, const int* in_sizes, int n_in,
                              void* d_out, int out_size, void* d_ws, size_t ws_size,
                              hipStream_t stream) {
  const float* h   = (const float*)d_in[0];
  const int*   row = (const int*)d_in[1];
  const int*   col = (const int*)d_in[2];
  const float* Win = (const float*)d_in[3];
  const float* bin = (const float*)d_in[4];
  const float* Wq  = (const float*)d_in[5];
  const float* bq  = (const float*)d_in[6];
  const float* Wk  = (const float*)d_in[7];
  const float* bk  = (const float*)d_in[8];
  const float* Wv  = (const float*)d_in[9];
  const float* bv  = (const float*)d_in[10];
  float* out = (float*)d_out;

  char* ws = (char*)d_ws;
  u16*   qkv     = (u16*)(ws + 0);           // 32768*1536*2 = 100,663,296
  u16*   hb      = (u16*)(ws + 100663296);   // 32768*512*2  =  33,554,432
  u16*   Wt      = (u16*)(ws + 134217728);   // 1536*512*2   =   1,572,864
  float* bias    = (float*)(ws + 135790592); // 1536*4
  int*   deg     = (int*)(ws + 135796736);   // 32768*4
  int*   row_ptr = (int*)(ws + 135927808);   // 32769*4 (+pad)
  int*   cursor  = (int*)(ws + 136058888);   // 32768*4
  int*   dst     = (int*)(ws + 136189960);   // 262144*4
  // transient (aliased into qkv region; consumed by gemm_wt BEFORE gemm_qkv
  // writes qkv — same-stream ordering makes this safe):
  u16*   At      = (u16*)(ws + 0);           // 1536*512*2 = 1,572,864
  u16*   Winb    = (u16*)(ws + 1572864);     //  512*512*2 =   524,288

  (void)hipMemsetAsync(deg, 0, NN * sizeof(int), stream);
  (void)hipMemsetAsync(bias, 0, NQKV * sizeof(float), stream);
  hipLaunchKernelGGL(prep_all,
                     dim3(GB_CASTH + GB_CASTW + GB_CNTD + GB_TCW + GB_BIAS),
                     dim3(256), 0, stream,
                     h, hb, Win, Winb, row, deg, Wq, Wk, Wv, At,
                     bin, bq, bk, bv, bias);
  hipLaunchKernelGGL(scan_deg,  dim3(1), dim3(1024), 0, stream, deg, row_ptr, cursor);
  hipLaunchKernelGGL(fill_csr,  dim3(EE / 256), dim3(256), 0, stream, row, col, cursor, dst);
  hipLaunchKernelGGL(gemm_wt,   dim3(512 / 128, 1536 / 128), dim3(256), 0, stream, At, Winb, Wt);
  hipLaunchKernelGGL(gemm_qkv,  dim3(NQKV / 256, NN / 256), dim3(512), 0, stream, hb, Wt, bias, qkv);
  hipLaunchKernelGGL(attn_agg,  dim3((NN * 64) / 256), dim3(256), 0, stream,
                     qkv, (const u32*)qkv, row_ptr, dst, out);
}